// Round 7
// baseline (921.129 us; speedup 1.0000x reference)
//
#include <hip/hip_runtime.h>
#include <math.h>
#include <stdio.h>
#include <stdint.h>

#define N_SRC 200000
#define N_DST 100000
#define NE    400000
// IN=128, H=8, D=32, H*D=256

#define SCAN_CHUNK 1024
#define NSCAN ((N_DST + SCAN_CHUNK - 1) / SCAN_CHUNK)   // 98

typedef short bf16x8 __attribute__((ext_vector_type(8)));
typedef float f32x4 __attribute__((ext_vector_type(4)));

__device__ __forceinline__ float bflo(unsigned int u) { return __uint_as_float(u << 16); }
__device__ __forceinline__ float bfhi(unsigned int u) { return __uint_as_float(u & 0xFFFF0000u); }
__device__ __forceinline__ unsigned short f2bf(float f) {
    unsigned int u = __float_as_uint(f);
    u += 0x7FFFu + ((u >> 16) & 1u);       // round-to-nearest-even
    return (unsigned short)(u >> 16);
}
// pack two f32 -> (bf16(f1)<<16)|bf16(f0) by truncation: single v_perm_b32
__device__ __forceinline__ unsigned int packbf(float f0, float f1) {
    return __builtin_amdgcn_perm(__float_as_uint(f1), __float_as_uint(f0), 0x07060302u);
}

// ---------------------------------------------------------------------------
// Staged MFMA GEMM with CONTIGUOUS-SLAB A staging.
// out[n][c] = sum_k A[n][k]*W[c][k] (+bias[c]+add_c[c]+add_n[n][c]).
// Key: block tile = 128 FULL rows, so the A tile (or K-half) is a contiguous
// byte range -> staged with perfectly-coalesced float4/uint4 streams (the
// 6.3TB/s pattern), converted to bf16 into LDS (+8 bf16 row pad: fragment
// reads are 2-way bank-aliased = free). MFMA phase: A from LDS, B streamed
// as 1KB-coalesced L2-resident fragments. HALVES>1 splits K to shrink LDS
// (43KB -> 3 blocks/CU) so stage/MFMA phases of different blocks overlap.
// A: f32 [N][K] (ABF=false) or bf16 [N][K] (ABF=true).
// ---------------------------------------------------------------------------
template<bool ABF, int K, int KP, int HALVES, int NT>
__global__ __launch_bounds__(256) void gemm_staged(
    const void* __restrict__ Ap, const unsigned short* __restrict__ Wf,
    const float* __restrict__ bias, const float* __restrict__ add_n,
    const float* __restrict__ add_c,
    unsigned short* __restrict__ out_lin, unsigned short* __restrict__ out_exp,
    int N, int C)
{
    constexpr int KST   = KP / 32;            // total k-steps
    constexpr int KSH   = KST / HALVES;       // k-steps per half
    constexpr int HALFW = KP / HALVES;        // elements per half
    constexpr int SRB   = (HALFW + 8) * 2;    // LDS row stride bytes (pad 16B)
    __shared__ __align__(16) char As[128 * SRB];

    const int tid  = threadIdx.x;
    const int lane = tid & 63;
    const int wv   = tid >> 6;
    const int fr   = lane & 15;
    const int fq   = lane >> 4;
    const int row0 = blockIdx.y * 128;
    const int nb0  = blockIdx.x * NT;

    f32x4 acc[2][NT];
#pragma unroll
    for (int m = 0; m < 2; ++m)
#pragma unroll
        for (int n = 0; n < NT; ++n) acc[m][n] = (f32x4){0.f, 0.f, 0.f, 0.f};

    for (int h = 0; h < HALVES; ++h) {
        if (h) __syncthreads();     // protect LDS reuse across halves
        // ---- stage: coalesced slab read -> bf16 -> LDS ----
        if (!ABF) {
            const float* Af = (const float*)Ap;
            constexpr int ROWF4 = HALFW / 4;
            constexpr int ITERS = (128 * ROWF4) / 256;
#pragma unroll 4
            for (int it = 0; it < ITERS; ++it) {
                int f   = it * 256 + tid;
                int row = f / ROWF4;            // const divisor -> magic mul
                int k4  = f - row * ROWF4;
                int rr  = row0 + row; if (rr >= N) rr = N - 1;
                int kk  = h * HALFW + k4 * 4;
                float4 v;
                if (KP == K || kk + 4 <= K) {
                    v = *(const float4*)&Af[(long)rr * K + kk];
                } else {
                    float t0 = (kk + 0 < K) ? Af[(long)rr * K + kk + 0] : 0.f;
                    float t1 = (kk + 1 < K) ? Af[(long)rr * K + kk + 1] : 0.f;
                    float t2 = (kk + 2 < K) ? Af[(long)rr * K + kk + 2] : 0.f;
                    float t3 = (kk + 3 < K) ? Af[(long)rr * K + kk + 3] : 0.f;
                    v = make_float4(t0, t1, t2, t3);
                }
                uint2 w;
                w.x = packbf(v.x, v.y);
                w.y = packbf(v.z, v.w);
                *(uint2*)(As + row * SRB + k4 * 8) = w;
            }
        } else {
            const unsigned short* Ab = (const unsigned short*)Ap;
            constexpr int ROWU4 = HALFW / 8;
            constexpr int ITERS = (128 * ROWU4) / 256;
#pragma unroll
            for (int it = 0; it < ITERS; ++it) {
                int f   = it * 256 + tid;
                int row = f / ROWU4;
                int u4  = f - row * ROWU4;
                int rr  = row0 + row; if (rr >= N) rr = N - 1;
                uint4 v = *(const uint4*)&Ab[(long)rr * K + h * HALFW + u4 * 8];
                *(uint4*)(As + row * SRB + u4 * 16) = v;
            }
        }
        __syncthreads();
        // ---- MFMA sweep over this half (no barriers inside) ----
#pragma unroll 2
        for (int ksl = 0; ksl < KSH; ++ksl) {
            const int ks = h * KSH + ksl;
            uint4 pb[NT];
#pragma unroll
            for (int n = 0; n < NT; ++n)
                pb[n] = *(const uint4*)&Wf[(size_t)(((nb0 + n) * KST + ks) * 64 + lane) * 8];
            bf16x8 a0 = *(const bf16x8*)(As + (wv * 32 +      fr) * SRB + ksl * 64 + fq * 16);
            bf16x8 a1 = *(const bf16x8*)(As + (wv * 32 + 16 + fr) * SRB + ksl * 64 + fq * 16);
#pragma unroll
            for (int n = 0; n < NT; ++n) {
                acc[0][n] = __builtin_amdgcn_mfma_f32_16x16x32_bf16(a0, *(bf16x8*)&pb[n], acc[0][n], 0, 0, 0);
                acc[1][n] = __builtin_amdgcn_mfma_f32_16x16x32_bf16(a1, *(bf16x8*)&pb[n], acc[1][n], 0, 0, 0);
            }
        }
    }

    // epilogue: D col = lane&15, row = (lane>>4)*4 + reg (measured m89/m91)
    float bc[NT];
#pragma unroll
    for (int n = 0; n < NT; ++n) {
        int col = (nb0 + n) * 16 + fr;
        float b = 0.f;
        if (bias)  b += bias[col];
        if (add_c) b += add_c[col];
        bc[n] = b;
    }
#pragma unroll
    for (int m = 0; m < 2; ++m) {
#pragma unroll
        for (int j = 0; j < 4; ++j) {
            int row = row0 + wv * 32 + m * 16 + fq * 4 + j;
            if (row >= N) continue;
#pragma unroll
            for (int n = 0; n < NT; ++n) {
                int col = (nb0 + n) * 16 + fr;
                float v = acc[m][n][j] + bc[n];
                if (add_n) v += add_n[(long)row * C + col];
                long o = (long)row * C + col;
                if (out_lin) out_lin[o] = f2bf(v);
                if (out_exp) out_exp[o] = f2bf(expf(v));
            }
        }
    }
}

// ---------------------------------------------------------------------------
// Weight f32 [C][K] -> bf16 B-fragment layout, zero-padded to Kp (KS=Kp/32):
// dst[((n*KS+ks)*64+l)*8 + j] = W[n*16 + (l&15)][ks*32 + (l>>4)*8 + j]
// ---------------------------------------------------------------------------
__global__ void wconv_frag(const float* __restrict__ src, unsigned short* __restrict__ dst,
                           int C, int K, int Kp)
{
    int KS = Kp >> 5;
    int total = C * Kp;
    for (int i = blockIdx.x * blockDim.x + threadIdx.x; i < total; i += gridDim.x * blockDim.x) {
        int j  = i & 7;
        int l  = (i >> 3) & 63;
        int t  = i >> 9;
        int ks = t % KS;
        int n  = t / KS;
        int col = n * 16 + (l & 15);
        int k   = ks * 32 + ((l >> 4) << 3) + j;
        dst[i] = (k < K) ? f2bf(src[(long)col * K + k]) : (unsigned short)0;
    }
}

// ---------------------------------------------------------------------------
// Setup: fold W_na into Q/K (wq_eff/wk_eff [8][128]), fold W_merge x W_eattn
// into Wcomb [8][128], cm[8] = b_merge + W_merge[:,8:] . b_eattn
// ---------------------------------------------------------------------------
__global__ void eff_setup(const float* __restrict__ Wq, const float* __restrict__ bq,
                          const float* __restrict__ na_item,
                          const float* __restrict__ Wk, const float* __restrict__ bk,
                          const float* __restrict__ na_user,
                          const float* __restrict__ W_merge, const float* __restrict__ b_merge,
                          const float* __restrict__ W_eattn, const float* __restrict__ b_eattn,
                          float* __restrict__ wq_eff, float* __restrict__ bq_eff,
                          float* __restrict__ wk_eff, float* __restrict__ bk_eff,
                          float* __restrict__ Wcomb, float* __restrict__ cmv)
{
    int tid = threadIdx.x;
    for (int idx = tid; idx < 1024; idx += 256) {
        int h = idx >> 7, k = idx & 127;
        float s1 = 0.f, s2 = 0.f, s3 = 0.f;
        for (int d = 0; d < 32; ++d) {
            s1 += Wq[(h * 32 + d) * 128 + k] * na_item[d];
            s2 += Wk[(h * 32 + d) * 128 + k] * na_user[d];
        }
        for (int j = 0; j < 8; ++j)
            s3 += W_merge[h * 16 + 8 + j] * W_eattn[j * 128 + k];
        wq_eff[idx] = s1;
        wk_eff[idx] = s2;
        Wcomb[idx]  = s3;
    }
    if (tid < 8) {
        float s1 = 0.f, s2 = 0.f, s3 = b_merge[tid];
        for (int d = 0; d < 32; ++d) {
            s1 += bq[tid * 32 + d] * na_item[d];
            s2 += bk[tid * 32 + d] * na_user[d];
        }
        for (int j = 0; j < 8; ++j) s3 += W_merge[tid * 16 + 8 + j] * b_eattn[j];
        bq_eff[tid] = s1;
        bk_eff[tid] = s2;
        cmv[tid]    = s3;
    }
}

// ---------------------------------------------------------------------------
// Wave-per-row 8-head dot from bf16 features, transpose-butterfly reduce.
// ---------------------------------------------------------------------------
__global__ __launch_bounds__(256) void rowdot8_bf(
    const unsigned short* __restrict__ feat, const float* __restrict__ weff,
    const float* __restrict__ beff, float* __restrict__ out, int N)
{
    int gw   = (blockIdx.x * blockDim.x + threadIdx.x) >> 6;
    int lane = threadIdx.x & 63;
    if (gw >= N) return;
    int ch = lane * 2;
    unsigned int u = *(const unsigned int*)&feat[(long)gw * 128 + ch];
    float x0 = bflo(u), x1 = bfhi(u);
    float part[8];
#pragma unroll
    for (int h = 0; h < 8; ++h)
        part[h] = x0 * weff[h * 128 + ch] + x1 * weff[h * 128 + ch + 1];
    int b0 = lane & 1, b1 = (lane >> 1) & 1, b2 = (lane >> 2) & 1;
    float u0 = (b0 ? part[1] : part[0]) + __shfl_xor(b0 ? part[0] : part[1], 1);
    float u1 = (b0 ? part[3] : part[2]) + __shfl_xor(b0 ? part[2] : part[3], 1);
    float u2 = (b0 ? part[5] : part[4]) + __shfl_xor(b0 ? part[4] : part[5], 1);
    float u3 = (b0 ? part[7] : part[6]) + __shfl_xor(b0 ? part[6] : part[7], 1);
    float w0 = (b1 ? u1 : u0) + __shfl_xor(b1 ? u0 : u1, 2);
    float w1 = (b1 ? u3 : u2) + __shfl_xor(b1 ? u2 : u3, 2);
    float ts = (b2 ? w1 : w0) + __shfl_xor(b2 ? w0 : w1, 4);
    ts += __shfl_xor(ts, 8);
    ts += __shfl_xor(ts, 16);
    ts += __shfl_xor(ts, 32);
    if (lane < 8) out[(long)gw * 8 + lane] = ts + beff[lane];
}

// ---------------------------------------------------------------------------
// CSR build: histogram -> two-level scan -> scatter
// ---------------------------------------------------------------------------
__global__ void hist_kernel(const int* __restrict__ dst_idx, int* __restrict__ cnt)
{
    int e = blockIdx.x * blockDim.x + threadIdx.x;
    if (e < NE) atomicAdd(&cnt[dst_idx[e]], 1);
}

__global__ __launch_bounds__(256) void blocksum_kernel(const int* __restrict__ cnt,
                                                       int* __restrict__ bsum)
{
    __shared__ int sm[256];
    int b = blockIdx.x, t = threadIdx.x;
    int s = 0;
    for (int i = t; i < SCAN_CHUNK; i += 256) {
        int idx = b * SCAN_CHUNK + i;
        if (idx < N_DST) s += cnt[idx];
    }
    sm[t] = s; __syncthreads();
    for (int off = 128; off > 0; off >>= 1) {
        if (t < off) sm[t] += sm[t + off];
        __syncthreads();
    }
    if (t == 0) bsum[b] = sm[0];
}

__global__ void scanoff_kernel(const int* __restrict__ bsum, int* __restrict__ boff)
{
    if (threadIdx.x == 0) {
        int r = 0;
        for (int i = 0; i < NSCAN; ++i) { boff[i] = r; r += bsum[i]; }
    }
}

__global__ __launch_bounds__(256) void rowstart_kernel(
    const int* __restrict__ cnt, const int* __restrict__ boff,
    int* __restrict__ row_start, int* __restrict__ cursor)
{
    __shared__ int sm[256];
    int b = blockIdx.x, t = threadIdx.x;
    int base = b * SCAN_CHUNK + t * 4;
    int c[4]; int tot = 0;
#pragma unroll
    for (int j = 0; j < 4; ++j) {
        int idx = base + j;
        c[j] = (idx < N_DST) ? cnt[idx] : 0;
        tot += c[j];
    }
    sm[t] = tot; __syncthreads();
    for (int off = 1; off < 256; off <<= 1) {
        int v = (t >= off) ? sm[t - off] : 0;
        __syncthreads();
        sm[t] += v;
        __syncthreads();
    }
    int run = sm[t] - tot + boff[b];
#pragma unroll
    for (int j = 0; j < 4; ++j) {
        int idx = base + j;
        if (idx < N_DST) { row_start[idx] = run; cursor[idx] = run; run += c[j]; }
    }
    if (b == 0 && t == 0) row_start[N_DST] = NE;
}

__global__ void scatter_kernel(const int* __restrict__ dst_idx,
                               int* __restrict__ cursor, int* __restrict__ eorder)
{
    int e = blockIdx.x * blockDim.x + threadIdx.x;
    if (e >= NE) return;
    int pos = atomicAdd(&cursor[dst_idx[e]], 1);
    eorder[pos] = e;
}

// ---------------------------------------------------------------------------
// Mega-fused gather v2: one wave per dst. z = P * esf (precomputed exps);
// Wcomb-folded temp path; transpose-butterfly reduce (10 shfl); LN epilogue.
// ---------------------------------------------------------------------------
__global__ __launch_bounds__(256) void fused_gather2(
    const int* __restrict__ row_start, const int* __restrict__ eorder,
    const int* __restrict__ src_idx,
    const unsigned short* __restrict__ Pb, const unsigned short* __restrict__ esfb,
    const unsigned short* __restrict__ vb,
    const float* __restrict__ aq, const float* __restrict__ ak,
    const float* __restrict__ Wcomb, const float* __restrict__ cmv,
    const float* __restrict__ W_merge,
    const float* __restrict__ ln_gamma, const float* __restrict__ ln_beta,
    float* __restrict__ out)
{
    int gw   = (blockIdx.x * blockDim.x + threadIdx.x) >> 6;
    int lane = threadIdx.x & 63;
    if (gw >= N_DST) return;
    const int dst = gw;
    const int r0 = row_start[dst], r1 = row_start[dst + 1];
    const int ch = lane * 2;
    const int hl = lane & 7;
    const int g  = lane >> 3;
    const float rsc = 0.17677669529663687f;   // 1/sqrt(32)

    float wc0[8], wc1[8];
#pragma unroll
    for (int h = 0; h < 8; ++h) {
        wc0[h] = Wcomb[h * 128 + ch];
        wc1[h] = Wcomb[h * 128 + ch + 1];
    }
    const float wself = W_merge[g * 16 + hl];
    const float cmg   = cmv[g];
    const float aqh   = aq[(long)dst * 8 + hl];

    // ---- pass 1: denominators ----
    float s1x = 0.f, s1y = 0.f, s2l = 0.f;
    int eo = 0, src = 0;
    if (r0 < r1) { eo = eorder[r0]; src = src_idx[eo]; }
    for (int j = r0; j < r1; ++j) {
        int eo_n = 0, src_n = 0;
        if (j + 1 < r1) { eo_n = eorder[j + 1]; src_n = src_idx[eo_n]; }
        unsigned int pe = *(const unsigned int*)&Pb[(long)eo * 128 + ch];
        unsigned int se = *(const unsigned int*)&esfb[(long)src * 128 + ch];
        float akh = ak[(long)src * 8 + hl];
        s1x += bflo(pe) * bflo(se);
        s1y += bfhi(pe) * bfhi(se);
        s2l += expf((akh + aqh) * rsc);
        eo = eo_n; src = src_n;
    }
    const float i1x = 1.0f / s1x, i1y = 1.0f / s1y, i2 = 1.0f / s2l;

    // ---- pass 2: attention + aggregate ----
    float ax = 0.f, ay = 0.f, az = 0.f, aw = 0.f;
    if (r0 < r1) { eo = eorder[r0]; src = src_idx[eo]; }
    for (int j = r0; j < r1; ++j) {
        int eo_n = 0, src_n = 0;
        if (j + 1 < r1) { eo_n = eorder[j + 1]; src_n = src_idx[eo_n]; }
        unsigned int pe = *(const unsigned int*)&Pb[(long)eo * 128 + ch];
        unsigned int se = *(const unsigned int*)&esfb[(long)src * 128 + ch];
        float akh = ak[(long)src * 8 + hl];
        uint2 vv = *(const uint2*)&vb[(long)src * 256 + lane * 4];
        float t0 = bflo(pe) * bflo(se) * i1x;
        float t1 = bfhi(pe) * bfhi(se) * i1y;
        float part[8];
#pragma unroll
        for (int h = 0; h < 8; ++h) part[h] = t0 * wc0[h] + t1 * wc1[h];
        // transpose-butterfly: 8 values over 64 lanes in 10 shfl
        int b0 = lane & 1, b1 = (lane >> 1) & 1, b2 = (lane >> 2) & 1;
        float u0 = (b0 ? part[1] : part[0]) + __shfl_xor(b0 ? part[0] : part[1], 1);
        float u1 = (b0 ? part[3] : part[2]) + __shfl_xor(b0 ? part[2] : part[3], 1);
        float u2 = (b0 ? part[5] : part[4]) + __shfl_xor(b0 ? part[4] : part[5], 1);
        float u3 = (b0 ? part[7] : part[6]) + __shfl_xor(b0 ? part[6] : part[7], 1);
        float w0 = (b1 ? u1 : u0) + __shfl_xor(b1 ? u0 : u1, 2);
        float w1 = (b1 ? u3 : u2) + __shfl_xor(b1 ? u2 : u3, 2);
        float ts = (b2 ? w1 : w0) + __shfl_xor(b2 ? w0 : w1, 4);
        ts += __shfl_xor(ts, 8);
        ts += __shfl_xor(ts, 16);
        ts += __shfl_xor(ts, 32);
        // self part: group-local 3-shfl reduce (head g = lane>>3)
        float sa = expf((akh + aqh) * rsc) * i2;
        float ms = wself * sa;
        ms += __shfl_xor(ms, 1);
        ms += __shfl_xor(ms, 2);
        ms += __shfl_xor(ms, 4);
        float mm = cmg + ms + __shfl(ts, g);
        ax += mm * bflo(vv.x); ay += mm * bfhi(vv.x);
        az += mm * bflo(vv.y); aw += mm * bfhi(vv.y);
        eo = eo_n; src = src_n;
    }

    // ---- LayerNorm epilogue ----
    float s = ax + ay + az + aw;
    float q = ax * ax + ay * ay + az * az + aw * aw;
#pragma unroll
    for (int off = 32; off > 0; off >>= 1) {
        s += __shfl_xor(s, off);
        q += __shfl_xor(q, off);
    }
    float mu  = s * (1.0f / 256.0f);
    float var = q * (1.0f / 256.0f) - mu * mu;
    float inv = rsqrtf(var + 1e-5f);
    float4 gg = *(const float4*)&ln_gamma[lane * 4];
    float4 bb = *(const float4*)&ln_beta[lane * 4];
    float4 o;
    o.x = (ax - mu) * inv * gg.x + bb.x;
    o.y = (ay - mu) * inv * gg.y + bb.y;
    o.z = (az - mu) * inv * gg.z + bb.z;
    o.w = (aw - mu) * inv * gg.w + bb.w;
    *(float4*)&out[(long)dst * 256 + lane * 4] = o;
}

// ---------------------------------------------------------------------------
extern "C" void kernel_launch(void* const* d_in, const int* in_sizes, int n_in,
                              void* d_out, int out_size, void* d_ws, size_t ws_size,
                              hipStream_t stream)
{
    const float* x_user        = (const float*)d_in[0];
    const float* x_item        = (const float*)d_in[1];
    const float* node_emb_user = (const float*)d_in[2];
    const float* edge_emb      = (const float*)d_in[3];
    const float* edge_feats    = (const float*)d_in[4];
    const int*   src_idx       = (const int*)d_in[5];
    const int*   dst_idx       = (const int*)d_in[6];
    const float* W_nf_user     = (const float*)d_in[7];
    const float* b_nf_user     = (const float*)d_in[8];
    const float* W_nf_item     = (const float*)d_in[9];
    const float* b_nf_item     = (const float*)d_in[10];
    const float* W_ef          = (const float*)d_in[11];
    const float* b_ef          = (const float*)d_in[12];
    const float* W_eattn       = (const float*)d_in[13];
    const float* b_eattn       = (const float*)d_in[14];
    const float* W_merge       = (const float*)d_in[15];
    const float* b_merge       = (const float*)d_in[16];
    const float* W_q           = (const float*)d_in[17];
    const float* b_q           = (const float*)d_in[18];
    const float* W_k           = (const float*)d_in[19];
    const float* b_k           = (const float*)d_in[20];
    const float* W_v           = (const float*)d_in[21];
    const float* b_v           = (const float*)d_in[22];
    const float* W_na_user     = (const float*)d_in[23];
    const float* W_na_item     = (const float*)d_in[24];
    const float* ln_gamma      = (const float*)d_in[25];
    const float* ln_beta       = (const float*)d_in[26];

    unsigned short* us   = (unsigned short*)d_ws;
    unsigned short* sf_b  = us;                    // 25,600,000  bf16 src_feat
    unsigned short* esf_b = sf_b + 25600000;       // 25,600,000  bf16 exp(src_feat)
    unsigned short* dsf_b = esf_b + 25600000;      // 12,800,000  bf16 dst_feat
    unsigned short* P_b   = dsf_b + 12800000;      // 51,200,000  bf16 exp(ef)
    unsigned short* v_b   = P_b + 51200000;        // 51,200,000  bf16 v
    float* fz     = (float*)(v_b + 51200000);
    float* aq     = fz;                            // 800,000
    float* ak     = aq + 800000;                   // 1,600,000
    float* wq_eff = ak + 1600000;                  // 1024
    float* wk_eff = wq_eff + 1024;                 // 1024
    float* bq_eff = wk_eff + 1024;                 // 16
    float* bk_eff = bq_eff + 16;                   // 16
    float* Wcomb  = bk_eff + 16;                   // 1024
    float* cmv    = Wcomb + 1024;                  // 8
    int*   cnt       = (int*)(cmv + 8);            // N_DST
    int*   bsum      = cnt + N_DST;                // 128
    int*   boff      = bsum + 128;                 // 128
    int*   row_start = boff + 128;                 // N_DST + 1
    int*   cursor    = row_start + N_DST + 1;      // N_DST
    int*   eorder    = cursor + N_DST;             // NE
    // W fragment buffers (16B-aligned for dwordx4 loads)
    unsigned short* wub = (unsigned short*)(((uintptr_t)(eorder + NE) + 15) & ~(uintptr_t)15);
    unsigned short* wib = wub + 128 * 320;
    unsigned short* web = wib + 128 * 224;
    unsigned short* wvb = web + 128 * 64;
    size_t needed = (size_t)((char*)(wvb + 256 * 128) - (char*)d_ws);
    if (ws_size < needed) {
        fprintf(stderr, "kernel_launch: ws_size %zu < needed %zu\n", ws_size, needed);
        return;
    }

    hipMemsetAsync(cnt, 0, N_DST * sizeof(int), stream);

    eff_setup<<<1, 256, 0, stream>>>(W_q, b_q, W_na_item, W_k, b_k, W_na_user,
                                     W_merge, b_merge, W_eattn, b_eattn,
                                     wq_eff, bq_eff, wk_eff, bk_eff, Wcomb, cmv);

    // weight pre-conversion to bf16 B-fragment layout (padded K)
    wconv_frag<<<64, 256, 0, stream>>>(W_nf_user, wub, 128, 300, 320);
    wconv_frag<<<64, 256, 0, stream>>>(W_nf_item, wib, 128, 200, 224);
    wconv_frag<<<32, 256, 0, stream>>>(W_ef,      web, 128,  64,  64);
    wconv_frag<<<64, 256, 0, stream>>>(W_v,       wvb, 256, 128, 128);

    // GEMM1: src_feat = x_user@W_nf_user^T + b + node_emb + edge_emb -> sf_b & esf_b
    gemm_staged<false, 300, 320, 2, 8><<<dim3(1, 1563), 256, 0, stream>>>(
        x_user, wub, b_nf_user, node_emb_user, edge_emb,
        sf_b, esf_b, N_SRC, 128);
    // GEMM2: dst_feat = x_item@W_nf_item^T + b + edge_emb -> dsf_b
    gemm_staged<false, 200, 224, 1, 8><<<dim3(1, 782), 256, 0, stream>>>(
        x_item, wib, b_nf_item, nullptr, edge_emb,
        dsf_b, nullptr, N_DST, 128);
    // GEMM3: P = exp(edge_feats@W_ef^T + b_ef) -> P_b
    gemm_staged<false, 64, 64, 1, 8><<<dim3(1, 3125), 256, 0, stream>>>(
        edge_feats, web, b_ef, nullptr, nullptr,
        nullptr, P_b, NE, 128);
    // GEMM4: v = sf@W_v^T + b_v -> v_b (A bf16; C=256 split over grid.x=2)
    gemm_staged<true, 128, 128, 1, 8><<<dim3(2, 1563), 256, 0, stream>>>(
        sf_b, wvb, b_v, nullptr, nullptr,
        v_b, nullptr, N_SRC, 256);

    // aq / ak via folded weights
    rowdot8_bf<<<25000, 256, 0, stream>>>(dsf_b, wq_eff, bq_eff, aq, N_DST);
    rowdot8_bf<<<50000, 256, 0, stream>>>(sf_b, wk_eff, bk_eff, ak, N_SRC);

    // CSR build
    hist_kernel<<<1563, 256, 0, stream>>>(dst_idx, cnt);
    blocksum_kernel<<<NSCAN, 256, 0, stream>>>(cnt, bsum);
    scanoff_kernel<<<1, 64, 0, stream>>>(bsum, boff);
    rowstart_kernel<<<NSCAN, 256, 0, stream>>>(cnt, boff, row_start, cursor);
    scatter_kernel<<<1563, 256, 0, stream>>>(dst_idx, cursor, eorder);

    // mega-fused gather + LN
    fused_gather2<<<25000, 256, 0, stream>>>(
        row_start, eorder, src_idx, P_b, esf_b, v_b, aq, ak,
        Wcomb, cmv, W_merge, ln_gamma, ln_beta, (float*)d_out);
}